// Round 12
// baseline (264.259 us; speedup 1.0000x reference)
//
#include <hip/hip_runtime.h>
#include <cstdint>
#include <cstddef>

namespace {

constexpr int kB    = 64;
constexpr int kN    = 1024;
constexpr int kE    = 655360;
constexpr int kEper = kE / kB;     // 10240
constexpr int kH    = 128;
constexpr int kK1   = 820;
constexpr int kK2   = 656;
constexpr int kM1   = kB * kN;     // 65536
constexpr int kM2   = kB * kK1;    // 52480

typedef __attribute__((ext_vector_type(8))) short bf16x8;
typedef __attribute__((ext_vector_type(4))) float f32x4;

__device__ inline ushort f2bf(float f) {            // fp32 -> bf16 RNE bits
  uint u = __float_as_uint(f);
  return (ushort)((u + 0x7fffu + ((u >> 16) & 1u)) >> 16);
}
__device__ inline float bf2f(ushort s) { return __uint_as_float(((uint)s) << 16); }

// packed hi/lo split of 4 floats via v_cvt_pk_bf16_f32 (absmax 0 since R6).
__device__ inline void cvt4(const float* f, uint* hh, uint* ll) {
#pragma unroll
  for (int i = 0; i < 2; ++i) {
    uint h;
    asm("v_cvt_pk_bf16_f32 %0, %1, %2" : "=v"(h) : "v"(f[2 * i]), "v"(f[2 * i + 1]));
    const float r0 = __uint_as_float(h << 16);
    const float r1 = __uint_as_float(h & 0xFFFF0000u);
    const float d0 = f[2 * i] - r0;
    const float d1 = f[2 * i + 1] - r1;
    uint l;
    asm("v_cvt_pk_bf16_f32 %0, %1, %2" : "=v"(l) : "v"(d0), "v"(d1));
    hh[i] = h; ll[i] = l;
  }
}

// direct global->LDS copy, 16B/lane (R10-proven). LDS dest wave-uniform base.
__device__ inline void llds16(const void* g, void* l) {
  __builtin_amdgcn_global_load_lds(
      (const __attribute__((address_space(1))) void*)g,
      (__attribute__((address_space(3))) void*)l, 16, 0, 0);
}

// inclusive block scan over 1024 threads: wave shfl-scan + 16-wavesum scan.
__device__ inline int block_scan_1024(int v, int* wsum /* LDS int[16] */) {
  const int lane = threadIdx.x & 63;
  const int w    = threadIdx.x >> 6;
#pragma unroll
  for (int off = 1; off < 64; off <<= 1) {
    const int n = __shfl_up(v, off);
    if (lane >= off) v += n;
  }
  if (lane == 63) wsum[w] = v;
  __syncthreads();
  if (w == 0) {
    int s = (lane < 16) ? wsum[lane] : 0;
#pragma unroll
    for (int off = 1; off < 16; off <<= 1) {
      const int n = __shfl_up(s, off);
      if (lane >= off) s += n;
    }
    if (lane < 16) wsum[lane] = s;
  }
  __syncthreads();
  if (w > 0) v += wsum[w - 1];
  return v;
}

// radix-select helper: returns threshold key T and rem (#==T to keep, by
// lowest index) for top-K of `key` over the block. Proven since R5.
__device__ inline void radix_select(uint key, int K, int* hist, uint* bTp,
                                    int* bRemp, uint& T, int& rem_out) {
  const int tid = threadIdx.x;
  uint prefix = 0;
  int rem = K;
#pragma unroll
  for (int shift = 24; shift >= 0; shift -= 8) {
    if (tid < 256) hist[tid] = 0;
    __syncthreads();
    const uint mask = (shift == 24) ? 0u : (0xFFFFFFFFu << (shift + 8));
    if ((key & mask) == prefix)
      atomicAdd(&hist[(key >> shift) & 255], 1);
    __syncthreads();
    if (tid < 64) {
      const int h0 = hist[4 * tid + 0], h1 = hist[4 * tid + 1];
      const int h2 = hist[4 * tid + 2], h3 = hist[4 * tid + 3];
      const int loc = h0 + h1 + h2 + h3;
      int suf = loc;
#pragma unroll
      for (int d = 1; d < 64; d <<= 1) {
        const int o = __shfl_down(suf, d);
        if (tid + d < 64) suf += o;
      }
      const int above = suf - loc;
      int hs[5];
      hs[4] = above;
      hs[3] = above + h3;
      hs[2] = hs[3] + h2;
      hs[1] = hs[2] + h1;
      hs[0] = hs[1] + h0;
#pragma unroll
      for (int q = 0; q < 4; ++q) {
        if (hs[q] >= rem && hs[q + 1] < rem) {   // unique crossing bin
          *bTp   = prefix | ((uint)(4 * tid + q) << shift);
          *bRemp = rem - hs[q + 1];
        }
      }
    }
    __syncthreads();
    prefix = *bTp;
    rem    = *bRemp;
    __syncthreads();
  }
  T = prefix;
  rem_out = rem;
}

__device__ inline uint score_key(float sc) {
  const uint bits = __float_as_uint(sc);
  return (bits & 0x80000000u) ? ~bits : (bits | 0x80000000u);
}

// ===== fused CSR build + weight prep: one launch, 129 blocks =====
__global__ __launch_bounds__(1024)
void build_prep(const int* __restrict__ src, const int* __restrict__ dst,
                int* __restrict__ coff, int* __restrict__ ccur,
                int* __restrict__ ent,
                const float* __restrict__ Wl1, const float* __restrict__ Wr1,
                const float* __restrict__ Wl2, const float* __restrict__ Wr2,
                const float* __restrict__ pw1, const float* __restrict__ pw2,
                ushort* __restrict__ W1h, ushort* __restrict__ W1l,
                ushort* __restrict__ W2h, ushort* __restrict__ W2l,
                float* __restrict__ pwn1, float* __restrict__ pwn2) {
  const int b   = blockIdx.x;
  const int tid = threadIdx.x;
  if (b >= 128) {                                    // pw normalize
    if (tid >= 256) return;
    const float* pw = (tid < 128) ? pw1 : pw2;
    float* o        = (tid < 128) ? pwn1 : pwn2;
    const int j = tid & 127;
    float sum = 0.0f;
    for (int k = 0; k < 128; ++k) { const float v = pw[k]; sum += v * v; }
    o[j] = pw[j] / sqrtf(sum);
    return;
  }
  if (b >= 64) {                                     // weight split
    const int ob  = (b - 64) * 4 + (tid >> 8);       // old prep block 0..255
    const bool l2 = ob >= 128;
    const int idx = (ob & 127) * 256 + (tid & 255);  // 0..32767
    const int n = idx >> 8, k = idx & 255;
    const float* Wl = l2 ? Wl2 : Wl1;
    const float* Wr = l2 ? Wr2 : Wr1;
    const float w = (k < 128) ? Wl[k * kH + n] : Wr[(k - 128) * kH + n];
    const ushort h = f2bf(w);
    (l2 ? W2h : W1h)[n * 256 + k] = h;
    (l2 ? W2l : W1l)[n * 256 + k] = f2bf(w - bf2f(h));
    return;
  }
  // ---- CSR build for graph b ----
  __shared__ int cnt[1024];
  __shared__ int wsum[16];
  const int g = b;
  const int ebase = g * kEper;
  cnt[tid] = 0;
  __syncthreads();
  for (int e = tid; e < kEper; e += 1024)
    atomicAdd(&cnt[dst[ebase + e] & (kN - 1)], 1);
  __syncthreads();
  const int dg   = cnt[tid];
  const int incl = block_scan_1024(dg, wsum);        // internal barriers
  const int start = ebase + incl - dg;               // exclusive scan
  coff[g * kN + tid] = start;
  ccur[g * kN + tid] = start + dg;                   // end offset
  __syncthreads();
  cnt[tid] = start;                                  // repurpose as cursor
  __syncthreads();
  for (int e = tid; e < kEper; e += 1024) {
    const int d   = dst[ebase + e] & (kN - 1);
    const int pos = atomicAdd(&cnt[d], 1);
    ent[pos] = src[ebase + e] & (kN - 1);
  }
}

// ================= LDS-staged gather-mean (llds16 staging) ==========
__global__ __launch_bounds__(1024, 8)
void gather1_lds(const float* __restrict__ feat, const int* __restrict__ ent,
                 const int* __restrict__ off, const int* __restrict__ cursor,
                 float* __restrict__ aggout) {
  __shared__ float cache[1024 * 16];                 // 64 KB, stride 16 floats
  const int xcd   = blockIdx.x & 7;
  const int local = blockIdx.x >> 3;
  const int graph = xcd * 8 + (local >> 3);
  const int chunk = local & 7;
  const int tid   = threadIdx.x;
  const int wid   = tid >> 6;
  const int gbase = graph << 10;

#pragma unroll
  for (int ps = 0; ps < 4; ++ps) {
    const int row = ps * 256 + (tid >> 2);
    const int q   = (tid & 3) * 4;
    llds16(feat + (size_t)(gbase + row) * kH + chunk * 16 + q,
           cache + ps * 4096 + wid * 256);
  }
  __syncthreads();

  const int grp = tid >> 2;            // group id 0..255 = node within iter
  const int q4  = (tid & 3) * 4;       // this lane's 4 cols inside the chunk

  for (int it = 0; it < 4; ++it) {
    const int lnode = it * 256 + grp;
    const int node  = gbase + lnode;
    const int o0 = off[node];
    const int o1 = cursor[node];
    const int deg = o1 - o0;
    float4 acc = make_float4(0.f, 0.f, 0.f, 0.f);
    int pf[4];
#pragma unroll
    for (int i = 0; i < 4; ++i) pf[i] = (o0 + i < o1) ? ent[o0 + i] : 0;
    for (int eb = 0; eb < deg; eb += 4) {
      int nx[4];
#pragma unroll
      for (int i = 0; i < 4; ++i) {
        const int idx = o0 + eb + 4 + i;
        nx[i] = (idx < o1) ? ent[idx] : 0;
      }
#pragma unroll
      for (int i = 0; i < 4; ++i) {
        const float m = (eb + i < deg) ? 1.0f : 0.0f;   // mask tail
        const float4 v = *(const float4*)&cache[pf[i] * 16 + q4];
        acc.x = fmaf(v.x, m, acc.x);
        acc.y = fmaf(v.y, m, acc.y);
        acc.z = fmaf(v.z, m, acc.z);
        acc.w = fmaf(v.w, m, acc.w);
      }
#pragma unroll
      for (int i = 0; i < 4; ++i) pf[i] = nx[i];
    }
    const float r = 1.0f / fmaxf((float)deg, 1.0f);
    const f32x4 res = {acc.x * r, acc.y * r, acc.z * r, acc.w * r};
    __builtin_nontemporal_store(res, (f32x4*)(aggout + (size_t)node * kH + chunk * 16 + q4));
  }
}

// layer-2 gather: llds16 staging + FUSED layer-1 readout epilogue (R11-proven).
__global__ __launch_bounds__(1024, 8)
void gather2_lds(const float* __restrict__ feat, const int* __restrict__ ent,
                 const int* __restrict__ off, const int* __restrict__ cursor,
                 const int* __restrict__ perm, const float* __restrict__ gsg,
                 float* __restrict__ aggout,
                 float* __restrict__ psumg, float* __restrict__ pmaxg) {
  __shared__ float cache[1024 * 16];                 // 64 KB
  __shared__ float gs[1024];                         // 4 KB gated scores
  __shared__ float rps[16][16], rpm[16][16];         // 2 KB readout partials
  const int xcd   = blockIdx.x & 7;
  const int local = blockIdx.x >> 3;
  const int graph = xcd * 8 + (local >> 3);
  const int chunk = local & 7;
  const int tid   = threadIdx.x;
  const int wid   = tid >> 6;
  const int gbase = graph << 10;

#pragma unroll
  for (int ps = 0; ps < 4; ++ps) {
    const int row = ps * 256 + (tid >> 2);
    const int q   = (tid & 3) * 4;
    llds16(feat + (size_t)(gbase + row) * kH + chunk * 16 + q,
           cache + ps * 4096 + wid * 256);
  }
  gs[tid] = gsg[gbase + tid];
  __syncthreads();

  const int grp = tid >> 2;
  const int q4  = (tid & 3) * 4;

  for (int it = 0; it < 4; ++it) {
    const int lnode = it * 256 + grp;                // valid < kK1 (820)
    int o0 = 0, o1 = 0;
    if (lnode < kK1) {
      const int orig = perm[graph * kK1 + lnode];
      o0 = off[orig];
      o1 = cursor[orig];
    }
    const int deg = o1 - o0;
    float4 acc = make_float4(0.f, 0.f, 0.f, 0.f);
    int cnt = 0;
    int pf[4];
#pragma unroll
    for (int i = 0; i < 4; ++i) pf[i] = (o0 + i < o1) ? ent[o0 + i] : 0;
    for (int eb = 0; eb < deg; eb += 4) {
      int nx[4];
#pragma unroll
      for (int i = 0; i < 4; ++i) {
        const int idx = o0 + eb + 4 + i;
        nx[i] = (idx < o1) ? ent[idx] : 0;
      }
#pragma unroll
      for (int i = 0; i < 4; ++i) {
        const float raw  = gs[pf[i]];
        const bool  kept = (raw > 0.5f) && (eb + i < deg);
        const float s    = kept ? raw - 2.0f : 0.0f;
        cnt += kept ? 1 : 0;
        const float4 v = *(const float4*)&cache[pf[i] * 16 + q4];
        acc.x = fmaf(v.x, s, acc.x);
        acc.y = fmaf(v.y, s, acc.y);
        acc.z = fmaf(v.z, s, acc.z);
        acc.w = fmaf(v.w, s, acc.w);
      }
#pragma unroll
      for (int i = 0; i < 4; ++i) pf[i] = nx[i];
    }
    const float r = 1.0f / fmaxf((float)cnt, 1.0f);
    const f32x4 res = {acc.x * r, acc.y * r, acc.z * r, acc.w * r};
    if (lnode < kK1)
      __builtin_nontemporal_store(res,
          (f32x4*)(aggout + (size_t)(graph * kK1 + lnode) * kH + chunk * 16 + q4));
  }

  // ---- fused layer-1 readout: gated sum/max over the LDS-resident slab ----
  __syncthreads();
  const int rcol = tid & 15;
  const int rseg = tid >> 4;                 // 0..63, 16 rows each
  float rs = 0.0f, rm = -1e30f;
#pragma unroll
  for (int i = 0; i < 16; ++i) {
    const int row = rseg * 16 + i;
    const float raw = gs[row];
    if (raw > 0.5f) {
      const float v = cache[row * 16 + rcol] * (raw - 2.0f);
      rs += v;
      rm = fmaxf(rm, v);
    }
  }
  rs += __shfl_xor(rs, 16); rs += __shfl_xor(rs, 32);
  rm = fmaxf(rm, __shfl_xor(rm, 16)); rm = fmaxf(rm, __shfl_xor(rm, 32));
  if ((tid & 48) == 0) { rps[wid][rcol] = rs; rpm[wid][rcol] = rm; }
  __syncthreads();
  if (tid < 16) {
    float ts = 0.0f, tm = -1e30f;
#pragma unroll
    for (int w = 0; w < 16; ++w) { ts += rps[w][tid]; tm = fmaxf(tm, rpm[w][tid]); }
    psumg[graph * kH + chunk * 16 + tid] = ts;
    pmaxg[graph * kH + chunk * 16 + tid] = tm;
  }
}

// ============ split-bf16 MFMA SAGE GEMM + fused score (R10/R11 proven) =======
__global__ __launch_bounds__(256)
void sage_gemm_mfma(const float* __restrict__ meanb, const float* __restrict__ xsrc,
                    const int* __restrict__ perm, const float* __restrict__ gsc,
                    const ushort* __restrict__ WTh, const ushort* __restrict__ WTl,
                    const float* __restrict__ bias, const float* __restrict__ pwn,
                    float* __restrict__ outp, float* __restrict__ scr) {
  __shared__ __align__(16) ushort aH[64][32];    // [row][k], 64 B row stride
  __shared__ __align__(16) ushort aL[64][32];
  __shared__ __align__(16) ushort wHs[128][32];  // [n][k] (= W^T)
  __shared__ __align__(16) ushort wLs[128][32];
  __shared__ float sdot[64][2];                  // [row][col-half] score partials
  const int tid  = threadIdx.x;
  const int wid  = tid >> 6;
  const int lane = tid & 63;
  const int quad = lane >> 4;
  const int l16  = lane & 15;
  const int rowbase = blockIdx.x * 64;
  const int wr = (wid >> 1) * 32;                // wave row offset (0/32)
  const int wc = (wid & 1) * 64;                 // wave col offset (0/64)

  const int n0a = wid * 32;
  const int n0b = wid * 32 + 16;
  const int wrowa = (n0a + (lane >> 2)) * 256 + (lane & 3) * 8;
  const int wrowb = (n0b + (lane >> 2)) * 256 + (lane & 3) * 8;

  int srow1[2]; float scl1[2];
#pragma unroll
  for (int i = 0; i < 2; ++i) {
    const int grow = rowbase + ((tid + i * 256) >> 3);
    srow1[i] = grow; scl1[i] = 1.0f;
    if (perm) { srow1[i] = perm[grow]; scl1[i] = gsc[grow]; }
  }

  f32x4 acc[2][4];
#pragma unroll
  for (int a = 0; a < 2; ++a)
#pragma unroll
    for (int b = 0; b < 4; ++b) acc[a][b] = (f32x4){0.f, 0.f, 0.f, 0.f};

  for (int s = 0; s < 8; ++s) {                  // 8 k-steps of 32 over K=256
    const bool ismean = s < 4;
    const float* sp = ismean ? meanb : xsrc;
    const int kbase = s * 32;
    const int kloc  = ismean ? kbase : kbase - 128;
#pragma unroll
    for (int i = 0; i < 2; ++i) {
      const int p   = tid + i * 256;
      const int row = p >> 3;
      const int k4  = (p & 7) * 4;
      const int srow   = ismean ? (rowbase + row) : srow1[i];
      const float scale = ismean ? 1.0f : scl1[i];
      const float4 v = *(const float4*)(sp + (size_t)srow * kH + kloc + k4);
      float f[4] = {v.x * scale, v.y * scale, v.z * scale, v.w * scale};
      uint hh[2], ll[2];
      cvt4(f, hh, ll);
      *(uint2*)&aH[row][k4] = make_uint2(hh[0], hh[1]);
      *(uint2*)&aL[row][k4] = make_uint2(ll[0], ll[1]);
    }
    llds16(WTh + wrowa + kbase, &wHs[n0a][0]);
    llds16(WTh + wrowb + kbase, &wHs[n0b][0]);
    llds16(WTl + wrowa + kbase, &wLs[n0a][0]);
    llds16(WTl + wrowb + kbase, &wLs[n0b][0]);
    __syncthreads();
    bf16x8 afh[2], afl[2];
#pragma unroll
    for (int rt = 0; rt < 2; ++rt) {
      afh[rt] = *(const bf16x8*)&aH[wr + rt * 16 + l16][quad * 8];
      afl[rt] = *(const bf16x8*)&aL[wr + rt * 16 + l16][quad * 8];
    }
#pragma unroll
    for (int ct = 0; ct < 4; ++ct) {
      const bf16x8 bh = *(const bf16x8*)&wHs[wc + ct * 16 + l16][quad * 8];
      const bf16x8 bl = *(const bf16x8*)&wLs[wc + ct * 16 + l16][quad * 8];
#pragma unroll
      for (int rt = 0; rt < 2; ++rt) {
        acc[rt][ct] = __builtin_amdgcn_mfma_f32_16x16x32_bf16(afh[rt], bh, acc[rt][ct], 0, 0, 0);
        acc[rt][ct] = __builtin_amdgcn_mfma_f32_16x16x32_bf16(afh[rt], bl, acc[rt][ct], 0, 0, 0);
        acc[rt][ct] = __builtin_amdgcn_mfma_f32_16x16x32_bf16(afl[rt], bh, acc[rt][ct], 0, 0, 0);
      }
    }
    __syncthreads();
  }
  float bv[4], pwv[4];
#pragma unroll
  for (int ct = 0; ct < 4; ++ct) {
    const int col = wc + ct * 16 + l16;
    bv[ct]  = bias[col];
    pwv[ct] = pwn[col];
  }
  float dot[2][4];
#pragma unroll
  for (int rt = 0; rt < 2; ++rt)
#pragma unroll
    for (int reg = 0; reg < 4; ++reg) dot[rt][reg] = 0.0f;
#pragma unroll
  for (int ct = 0; ct < 4; ++ct) {
    const int col = wc + ct * 16 + l16;
#pragma unroll
    for (int rt = 0; rt < 2; ++rt) {
#pragma unroll
      for (int reg = 0; reg < 4; ++reg) {
        const int row = rowbase + wr + rt * 16 + quad * 4 + reg;
        const float o = fmaxf(acc[rt][ct][reg] + bv[ct], 0.0f);
        outp[(size_t)row * kH + col] = o;
        dot[rt][reg] += o * pwv[ct];
      }
    }
  }
#pragma unroll
  for (int rt = 0; rt < 2; ++rt) {
#pragma unroll
    for (int reg = 0; reg < 4; ++reg) {
      float d = dot[rt][reg];
      d += __shfl_xor(d, 1);
      d += __shfl_xor(d, 2);
      d += __shfl_xor(d, 4);
      d += __shfl_xor(d, 8);
      if (l16 == 0) sdot[wr + rt * 16 + quad * 4 + reg][wc >> 6] = d;
    }
  }
  __syncthreads();
  if (tid < 64) scr[rowbase + tid] = tanhf(sdot[tid][0] + sdot[tid][1]);
}

// ====== layer-1 top-K rank + compaction (radix select; proven since R5) =====
__global__ __launch_bounds__(1024)
void rank_compact(const float* __restrict__ scr, int n_per, int K,
                  int* __restrict__ perm, float* __restrict__ gsc,
                  float* __restrict__ gsg) {
  __shared__ int hist[256];
  __shared__ int wsum[16];
  __shared__ uint bT;
  __shared__ int bRem;
  const int g = blockIdx.x, tid = threadIdx.x;
  const float sc = (tid < n_per) ? scr[g * n_per + tid] : -3e30f;  // pad never wins
  const uint key = score_key(sc);

  uint T; int rem;
  radix_select(key, K, hist, &bT, &bRem, T, rem);

  const int gt = (key > T) ? 1 : 0;
  const int eq = (key == T) ? 1 : 0;
  const int incl = block_scan_1024((gt << 11) | eq, wsum);   // internal barriers
  const int excl = incl - ((gt << 11) | eq);
  const int gt_excl = excl >> 11;
  const int eq_excl = excl & 2047;
  const int keep = (tid < n_per) && (gt || (eq && eq_excl < rem));
  if (keep) {
    const int pos = gt_excl + min(eq_excl, rem);
    perm[g * K + pos] = g * n_per + tid;
    gsc[g * K + pos]  = sc;
  }
  if (gsg) gsg[g * kN + tid] = keep ? sc + 2.0f : 0.0f;
}

// ====== R22: fused layer-2 tail — radix-select + gated readout + MLP head ====
// Replaces rank_compact(L2) + readout_part(L2) + final_mlp (3 launches -> 1).
// Gate table lives in LDS only (no perm2/gsc2/psum2/pmax2 globals at all).
__global__ __launch_bounds__(1024)
void final_fused(const float* __restrict__ scr, const float* __restrict__ h2,
                 const float* __restrict__ ps1, const float* __restrict__ pm1,
                 const float* __restrict__ fW1, const float* __restrict__ fb1,
                 const float* __restrict__ fW2, const float* __restrict__ fb2,
                 float* __restrict__ out) {
  __shared__ int hist[256];
  __shared__ int wsum[16];
  __shared__ uint bT;
  __shared__ int bRem;
  __shared__ float ls[1024];                 // gated scores (+2 sentinel)
  __shared__ float ss[8][128], sm[8][128];   // readout partials
  __shared__ float xx[256];
  __shared__ float z[128];
  const int g = blockIdx.x, tid = threadIdx.x;
  const int n_per = kK1, K = kK2;

  // ---- top-K select over layer-2 scores ----
  const float sc = (tid < n_per) ? scr[g * n_per + tid] : -3e30f;
  const uint key = score_key(sc);
  uint T; int rem;
  radix_select(key, K, hist, &bT, &bRem, T, rem);
  const int gt = (key > T) ? 1 : 0;
  const int eq = (key == T) ? 1 : 0;
  const int eq_incl = block_scan_1024(eq, wsum);     // tie-break needs eq order
  const int eq_excl = eq_incl - eq;
  const int keep = (tid < n_per) && (gt || (eq && eq_excl < rem));
  ls[tid] = keep ? sc + 2.0f : 0.0f;
  __syncthreads();

  // ---- gated readout of h2 rows g*kK1 + i (8 parts x 128 cols, coalesced) ----
  const int part = tid >> 7;
  const int j    = tid & 127;
  float sum = 0.0f, mx = -1e30f;
  for (int i = part; i < n_per; i += 8) {
    const float raw = ls[i];
    if (raw > 0.5f) {
      const float v = h2[(size_t)(g * kK1 + i) * kH + j] * (raw - 2.0f);
      sum += v;
      mx = fmaxf(mx, v);
    }
  }
  ss[part][j] = sum;
  sm[part][j] = mx;
  __syncthreads();

  // ---- combine with layer-1 readout + 2-layer MLP head ----
  if (tid < 128) {
    float s2 = 0.0f, m2 = -1e30f;
#pragma unroll
    for (int p = 0; p < 8; ++p) { s2 += ss[p][tid]; m2 = fmaxf(m2, sm[p][tid]); }
    const float s1 = ps1[(size_t)g * 128 + tid];
    const float m1 = pm1[(size_t)g * 128 + tid];
    xx[tid]       = s1 / (float)kK1 + s2 / (float)K;
    xx[tid + 128] = m1 + m2;
  }
  __syncthreads();
  if (tid < 128) {
    float a = fb1[tid];
    for (int k = 0; k < 256; ++k) a += xx[k] * fW1[k * 128 + tid];
    z[tid] = fmaxf(a, 0.0f);
  }
  __syncthreads();
  if (tid < 10) {
    float o = fb2[tid];
    for (int k = 0; k < 128; ++k) o += z[k] * fW2[k * 10 + tid];
    out[g * 10 + tid] = o;
  }
}

}  // namespace

extern "C" void kernel_launch(void* const* d_in, const int* in_sizes, int n_in,
                              void* d_out, int out_size, void* d_ws, size_t ws_size,
                              hipStream_t stream) {
  const float* x   = (const float*)d_in[0];
  const int*   ei  = (const int*)d_in[1];
  const float* Wl1 = (const float*)d_in[3];
  const float* bl1 = (const float*)d_in[4];
  const float* Wr1 = (const float*)d_in[5];
  const float* Wl2 = (const float*)d_in[6];
  const float* bl2 = (const float*)d_in[7];
  const float* Wr2 = (const float*)d_in[8];
  const float* pw1 = (const float*)d_in[9];
  const float* pw2 = (const float*)d_in[10];
  const float* fW1 = (const float*)d_in[11];
  const float* fb1 = (const float*)d_in[12];
  const float* fW2 = (const float*)d_in[13];
  const float* fb2 = (const float*)d_in[14];
  const int* src = ei;
  const int* dst = ei + kE;
  (void)in_sizes; (void)n_in; (void)out_size; (void)ws_size;

  char* wsb = (char*)d_ws;
  size_t off_b = 0;
  auto alloc = [&](size_t bytes) {
    void* p = wsb + off_b;
    off_b += (bytes + 255) & ~(size_t)255;
    return p;
  };
  float* bufA = (float*)alloc((size_t)kM1 * kH * 4);  // mean1 -> mean2
  float* bufB = (float*)alloc((size_t)kM1 * kH * 4);  // h1
  float* bufC = (float*)alloc((size_t)kM2 * kH * 4);  // h2
  int*   coff = (int*)alloc((size_t)kM1 * 4);
  int*   ccur = (int*)alloc((size_t)kM1 * 4);
  int*   ent  = (int*)alloc((size_t)kE * 4);
  float* scr  = (float*)alloc((size_t)kM1 * 4);
  float* gsg  = (float*)alloc((size_t)kM1 * 4);
  int*   perm1= (int*)alloc((size_t)kM2 * 4);
  float* gsc1 = (float*)alloc((size_t)kM2 * 4);
  float* psum1= (float*)alloc((size_t)kB * 128 * 4);  // L1: fully reduced
  float* pmax1= (float*)alloc((size_t)kB * 128 * 4);
  ushort* wt1h = (ushort*)alloc((size_t)128 * 256 * 2);
  ushort* wt1l = (ushort*)alloc((size_t)128 * 256 * 2);
  ushort* wt2h = (ushort*)alloc((size_t)128 * 256 * 2);
  ushort* wt2l = (ushort*)alloc((size_t)128 * 256 * 2);
  float* pwn1 = (float*)alloc(128 * 4);
  float* pwn2 = (float*)alloc(128 * 4);

  // ---------------- fused CSR build + prep ----------------
  build_prep<<<129, 1024, 0, stream>>>(src, dst, coff, ccur, ent,
                                       Wl1, Wr1, Wl2, Wr2, pw1, pw2,
                                       wt1h, wt1l, wt2h, wt2l, pwn1, pwn2);

  // ---------------- layer 1 ----------------
  gather1_lds<<<kB * 8, 1024, 0, stream>>>(x, ent, coff, ccur, bufA);
  sage_gemm_mfma<<<kM1 / 64, 256, 0, stream>>>(bufA, x, nullptr, nullptr,
                                               wt1h, wt1l, bl1, pwn1, bufB, scr);
  rank_compact<<<kB, 1024, 0, stream>>>(scr, kN, kK1, perm1, gsc1, gsg);

  // ---------------- layer 2 (gather2 also emits the layer-1 readout) --------
  gather2_lds<<<kB * 8, 1024, 0, stream>>>(bufB, ent, coff, ccur, perm1, gsg,
                                           bufA, psum1, pmax1);
  sage_gemm_mfma<<<kM2 / 64, 256, 0, stream>>>(bufA, bufB, perm1, gsc1,
                                               wt2h, wt2l, bl2, pwn2, bufC, scr);

  // ---------------- fused tail: L2 rank + gated readout + MLP head ----------
  final_fused<<<kB, 1024, 0, stream>>>(scr, bufC, psum1, pmax1,
                                       fW1, fb1, fW2, fb2, (float*)d_out);
}

// Round 13
// 238.355 us; speedup vs baseline: 1.1087x; 1.1087x over previous
//
#include <hip/hip_runtime.h>
#include <cstdint>
#include <cstddef>

namespace {

constexpr int kB    = 64;
constexpr int kN    = 1024;
constexpr int kE    = 655360;
constexpr int kEper = kE / kB;     // 10240
constexpr int kH    = 128;
constexpr int kK1   = 820;
constexpr int kK2   = 656;
constexpr int kM1   = kB * kN;     // 65536
constexpr int kM2   = kB * kK1;    // 52480

typedef __attribute__((ext_vector_type(8))) short bf16x8;
typedef __attribute__((ext_vector_type(4))) float f32x4;

__device__ inline ushort f2bf(float f) {            // fp32 -> bf16 RNE bits
  uint u = __float_as_uint(f);
  return (ushort)((u + 0x7fffu + ((u >> 16) & 1u)) >> 16);
}
__device__ inline float bf2f(ushort s) { return __uint_as_float(((uint)s) << 16); }

// packed hi/lo split of 4 floats via v_cvt_pk_bf16_f32 (absmax 0 since R6).
__device__ inline void cvt4(const float* f, uint* hh, uint* ll) {
#pragma unroll
  for (int i = 0; i < 2; ++i) {
    uint h;
    asm("v_cvt_pk_bf16_f32 %0, %1, %2" : "=v"(h) : "v"(f[2 * i]), "v"(f[2 * i + 1]));
    const float r0 = __uint_as_float(h << 16);
    const float r1 = __uint_as_float(h & 0xFFFF0000u);
    const float d0 = f[2 * i] - r0;
    const float d1 = f[2 * i + 1] - r1;
    uint l;
    asm("v_cvt_pk_bf16_f32 %0, %1, %2" : "=v"(l) : "v"(d0), "v"(d1));
    hh[i] = h; ll[i] = l;
  }
}

// direct global->LDS copy, 16B/lane (R10-proven). LDS dest wave-uniform base.
__device__ inline void llds16(const void* g, void* l) {
  __builtin_amdgcn_global_load_lds(
      (const __attribute__((address_space(1))) void*)g,
      (__attribute__((address_space(3))) void*)l, 16, 0, 0);
}

// inclusive block scan over 1024 threads: wave shfl-scan + 16-wavesum scan.
__device__ inline int block_scan_1024(int v, int* wsum /* LDS int[16] */) {
  const int lane = threadIdx.x & 63;
  const int w    = threadIdx.x >> 6;
#pragma unroll
  for (int off = 1; off < 64; off <<= 1) {
    const int n = __shfl_up(v, off);
    if (lane >= off) v += n;
  }
  if (lane == 63) wsum[w] = v;
  __syncthreads();
  if (w == 0) {
    int s = (lane < 16) ? wsum[lane] : 0;
#pragma unroll
    for (int off = 1; off < 16; off <<= 1) {
      const int n = __shfl_up(s, off);
      if (lane >= off) s += n;
    }
    if (lane < 16) wsum[lane] = s;
  }
  __syncthreads();
  if (w > 0) v += wsum[w - 1];
  return v;
}

// radix-select helper: returns threshold key T and rem (#==T to keep, by
// lowest index) for top-K of `key` over the block. Proven since R5.
__device__ inline void radix_select(uint key, int K, int* hist, uint* bTp,
                                    int* bRemp, uint& T, int& rem_out) {
  const int tid = threadIdx.x;
  uint prefix = 0;
  int rem = K;
#pragma unroll
  for (int shift = 24; shift >= 0; shift -= 8) {
    if (tid < 256) hist[tid] = 0;
    __syncthreads();
    const uint mask = (shift == 24) ? 0u : (0xFFFFFFFFu << (shift + 8));
    if ((key & mask) == prefix)
      atomicAdd(&hist[(key >> shift) & 255], 1);
    __syncthreads();
    if (tid < 64) {
      const int h0 = hist[4 * tid + 0], h1 = hist[4 * tid + 1];
      const int h2 = hist[4 * tid + 2], h3 = hist[4 * tid + 3];
      const int loc = h0 + h1 + h2 + h3;
      int suf = loc;
#pragma unroll
      for (int d = 1; d < 64; d <<= 1) {
        const int o = __shfl_down(suf, d);
        if (tid + d < 64) suf += o;
      }
      const int above = suf - loc;
      int hs[5];
      hs[4] = above;
      hs[3] = above + h3;
      hs[2] = hs[3] + h2;
      hs[1] = hs[2] + h1;
      hs[0] = hs[1] + h0;
#pragma unroll
      for (int q = 0; q < 4; ++q) {
        if (hs[q] >= rem && hs[q + 1] < rem) {   // unique crossing bin
          *bTp   = prefix | ((uint)(4 * tid + q) << shift);
          *bRemp = rem - hs[q + 1];
        }
      }
    }
    __syncthreads();
    prefix = *bTp;
    rem    = *bRemp;
    __syncthreads();
  }
  T = prefix;
  rem_out = rem;
}

__device__ inline uint score_key(float sc) {
  const uint bits = __float_as_uint(sc);
  return (bits & 0x80000000u) ? ~bits : (bits | 0x80000000u);
}

// ===== fused CSR build + weight prep: one launch, 129 blocks =====
__global__ __launch_bounds__(1024)
void build_prep(const int* __restrict__ src, const int* __restrict__ dst,
                int* __restrict__ coff, int* __restrict__ ccur,
                int* __restrict__ ent,
                const float* __restrict__ Wl1, const float* __restrict__ Wr1,
                const float* __restrict__ Wl2, const float* __restrict__ Wr2,
                const float* __restrict__ pw1, const float* __restrict__ pw2,
                ushort* __restrict__ W1h, ushort* __restrict__ W1l,
                ushort* __restrict__ W2h, ushort* __restrict__ W2l,
                float* __restrict__ pwn1, float* __restrict__ pwn2) {
  const int b   = blockIdx.x;
  const int tid = threadIdx.x;
  if (b >= 128) {                                    // pw normalize
    if (tid >= 256) return;
    const float* pw = (tid < 128) ? pw1 : pw2;
    float* o        = (tid < 128) ? pwn1 : pwn2;
    const int j = tid & 127;
    float sum = 0.0f;
    for (int k = 0; k < 128; ++k) { const float v = pw[k]; sum += v * v; }
    o[j] = pw[j] / sqrtf(sum);
    return;
  }
  if (b >= 64) {                                     // weight split
    const int ob  = (b - 64) * 4 + (tid >> 8);       // old prep block 0..255
    const bool l2 = ob >= 128;
    const int idx = (ob & 127) * 256 + (tid & 255);  // 0..32767
    const int n = idx >> 8, k = idx & 255;
    const float* Wl = l2 ? Wl2 : Wl1;
    const float* Wr = l2 ? Wr2 : Wr1;
    const float w = (k < 128) ? Wl[k * kH + n] : Wr[(k - 128) * kH + n];
    const ushort h = f2bf(w);
    (l2 ? W2h : W1h)[n * 256 + k] = h;
    (l2 ? W2l : W1l)[n * 256 + k] = f2bf(w - bf2f(h));
    return;
  }
  // ---- CSR build for graph b ----
  __shared__ int cnt[1024];
  __shared__ int wsum[16];
  const int g = b;
  const int ebase = g * kEper;
  cnt[tid] = 0;
  __syncthreads();
  for (int e = tid; e < kEper; e += 1024)
    atomicAdd(&cnt[dst[ebase + e] & (kN - 1)], 1);
  __syncthreads();
  const int dg   = cnt[tid];
  const int incl = block_scan_1024(dg, wsum);        // internal barriers
  const int start = ebase + incl - dg;               // exclusive scan
  coff[g * kN + tid] = start;
  ccur[g * kN + tid] = start + dg;                   // end offset
  __syncthreads();
  cnt[tid] = start;                                  // repurpose as cursor
  __syncthreads();
  for (int e = tid; e < kEper; e += 1024) {
    const int d   = dst[ebase + e] & (kN - 1);
    const int pos = atomicAdd(&cnt[d], 1);
    ent[pos] = src[ebase + e] & (kN - 1);
  }
}

// ================= LDS-staged gather-mean (llds16 staging) ==========
__global__ __launch_bounds__(1024, 8)
void gather1_lds(const float* __restrict__ feat, const int* __restrict__ ent,
                 const int* __restrict__ off, const int* __restrict__ cursor,
                 float* __restrict__ aggout) {
  __shared__ float cache[1024 * 16];                 // 64 KB, stride 16 floats
  const int xcd   = blockIdx.x & 7;
  const int local = blockIdx.x >> 3;
  const int graph = xcd * 8 + (local >> 3);
  const int chunk = local & 7;
  const int tid   = threadIdx.x;
  const int wid   = tid >> 6;
  const int gbase = graph << 10;

#pragma unroll
  for (int ps = 0; ps < 4; ++ps) {
    const int row = ps * 256 + (tid >> 2);
    const int q   = (tid & 3) * 4;
    llds16(feat + (size_t)(gbase + row) * kH + chunk * 16 + q,
           cache + ps * 4096 + wid * 256);
  }
  __syncthreads();

  const int grp = tid >> 2;            // group id 0..255 = node within iter
  const int q4  = (tid & 3) * 4;       // this lane's 4 cols inside the chunk

  for (int it = 0; it < 4; ++it) {
    const int lnode = it * 256 + grp;
    const int node  = gbase + lnode;
    const int o0 = off[node];
    const int o1 = cursor[node];
    const int deg = o1 - o0;
    float4 acc = make_float4(0.f, 0.f, 0.f, 0.f);
    int pf[4];
#pragma unroll
    for (int i = 0; i < 4; ++i) pf[i] = (o0 + i < o1) ? ent[o0 + i] : 0;
    for (int eb = 0; eb < deg; eb += 4) {
      int nx[4];
#pragma unroll
      for (int i = 0; i < 4; ++i) {
        const int idx = o0 + eb + 4 + i;
        nx[i] = (idx < o1) ? ent[idx] : 0;
      }
#pragma unroll
      for (int i = 0; i < 4; ++i) {
        const float m = (eb + i < deg) ? 1.0f : 0.0f;   // mask tail
        const float4 v = *(const float4*)&cache[pf[i] * 16 + q4];
        acc.x = fmaf(v.x, m, acc.x);
        acc.y = fmaf(v.y, m, acc.y);
        acc.z = fmaf(v.z, m, acc.z);
        acc.w = fmaf(v.w, m, acc.w);
      }
#pragma unroll
      for (int i = 0; i < 4; ++i) pf[i] = nx[i];
    }
    const float r = 1.0f / fmaxf((float)deg, 1.0f);
    const f32x4 res = {acc.x * r, acc.y * r, acc.z * r, acc.w * r};
    __builtin_nontemporal_store(res, (f32x4*)(aggout + (size_t)node * kH + chunk * 16 + q4));
  }
}

// layer-2 gather: llds16 staging + FUSED layer-1 readout epilogue (R11-proven).
__global__ __launch_bounds__(1024, 8)
void gather2_lds(const float* __restrict__ feat, const int* __restrict__ ent,
                 const int* __restrict__ off, const int* __restrict__ cursor,
                 const int* __restrict__ perm, const float* __restrict__ gsg,
                 float* __restrict__ aggout,
                 float* __restrict__ psumg, float* __restrict__ pmaxg) {
  __shared__ float cache[1024 * 16];                 // 64 KB
  __shared__ float gs[1024];                         // 4 KB gated scores
  __shared__ float rps[16][16], rpm[16][16];         // 2 KB readout partials
  const int xcd   = blockIdx.x & 7;
  const int local = blockIdx.x >> 3;
  const int graph = xcd * 8 + (local >> 3);
  const int chunk = local & 7;
  const int tid   = threadIdx.x;
  const int wid   = tid >> 6;
  const int gbase = graph << 10;

#pragma unroll
  for (int ps = 0; ps < 4; ++ps) {
    const int row = ps * 256 + (tid >> 2);
    const int q   = (tid & 3) * 4;
    llds16(feat + (size_t)(gbase + row) * kH + chunk * 16 + q,
           cache + ps * 4096 + wid * 256);
  }
  gs[tid] = gsg[gbase + tid];
  __syncthreads();

  const int grp = tid >> 2;
  const int q4  = (tid & 3) * 4;

  for (int it = 0; it < 4; ++it) {
    const int lnode = it * 256 + grp;                // valid < kK1 (820)
    int o0 = 0, o1 = 0;
    if (lnode < kK1) {
      const int orig = perm[graph * kK1 + lnode];
      o0 = off[orig];
      o1 = cursor[orig];
    }
    const int deg = o1 - o0;
    float4 acc = make_float4(0.f, 0.f, 0.f, 0.f);
    int cnt = 0;
    int pf[4];
#pragma unroll
    for (int i = 0; i < 4; ++i) pf[i] = (o0 + i < o1) ? ent[o0 + i] : 0;
    for (int eb = 0; eb < deg; eb += 4) {
      int nx[4];
#pragma unroll
      for (int i = 0; i < 4; ++i) {
        const int idx = o0 + eb + 4 + i;
        nx[i] = (idx < o1) ? ent[idx] : 0;
      }
#pragma unroll
      for (int i = 0; i < 4; ++i) {
        const float raw  = gs[pf[i]];
        const bool  kept = (raw > 0.5f) && (eb + i < deg);
        const float s    = kept ? raw - 2.0f : 0.0f;
        cnt += kept ? 1 : 0;
        const float4 v = *(const float4*)&cache[pf[i] * 16 + q4];
        acc.x = fmaf(v.x, s, acc.x);
        acc.y = fmaf(v.y, s, acc.y);
        acc.z = fmaf(v.z, s, acc.z);
        acc.w = fmaf(v.w, s, acc.w);
      }
#pragma unroll
      for (int i = 0; i < 4; ++i) pf[i] = nx[i];
    }
    const float r = 1.0f / fmaxf((float)cnt, 1.0f);
    const f32x4 res = {acc.x * r, acc.y * r, acc.z * r, acc.w * r};
    if (lnode < kK1)
      __builtin_nontemporal_store(res,
          (f32x4*)(aggout + (size_t)(graph * kK1 + lnode) * kH + chunk * 16 + q4));
  }

  // ---- fused layer-1 readout: gated sum/max over the LDS-resident slab ----
  __syncthreads();
  const int rcol = tid & 15;
  const int rseg = tid >> 4;                 // 0..63, 16 rows each
  float rs = 0.0f, rm = -1e30f;
#pragma unroll
  for (int i = 0; i < 16; ++i) {
    const int row = rseg * 16 + i;
    const float raw = gs[row];
    if (raw > 0.5f) {
      const float v = cache[row * 16 + rcol] * (raw - 2.0f);
      rs += v;
      rm = fmaxf(rm, v);
    }
  }
  rs += __shfl_xor(rs, 16); rs += __shfl_xor(rs, 32);
  rm = fmaxf(rm, __shfl_xor(rm, 16)); rm = fmaxf(rm, __shfl_xor(rm, 32));
  if ((tid & 48) == 0) { rps[wid][rcol] = rs; rpm[wid][rcol] = rm; }
  __syncthreads();
  if (tid < 16) {
    float ts = 0.0f, tm = -1e30f;
#pragma unroll
    for (int w = 0; w < 16; ++w) { ts += rps[w][tid]; tm = fmaxf(tm, rpm[w][tid]); }
    psumg[graph * kH + chunk * 16 + tid] = ts;
    pmaxg[graph * kH + chunk * 16 + tid] = tm;
  }
}

// ============ split-bf16 MFMA SAGE GEMM + fused score (R10/R11 proven) =======
__global__ __launch_bounds__(256)
void sage_gemm_mfma(const float* __restrict__ meanb, const float* __restrict__ xsrc,
                    const int* __restrict__ perm, const float* __restrict__ gsc,
                    const ushort* __restrict__ WTh, const ushort* __restrict__ WTl,
                    const float* __restrict__ bias, const float* __restrict__ pwn,
                    float* __restrict__ outp, float* __restrict__ scr) {
  __shared__ __align__(16) ushort aH[64][32];    // [row][k], 64 B row stride
  __shared__ __align__(16) ushort aL[64][32];
  __shared__ __align__(16) ushort wHs[128][32];  // [n][k] (= W^T)
  __shared__ __align__(16) ushort wLs[128][32];
  __shared__ float sdot[64][2];                  // [row][col-half] score partials
  const int tid  = threadIdx.x;
  const int wid  = tid >> 6;
  const int lane = tid & 63;
  const int quad = lane >> 4;
  const int l16  = lane & 15;
  const int rowbase = blockIdx.x * 64;
  const int wr = (wid >> 1) * 32;                // wave row offset (0/32)
  const int wc = (wid & 1) * 64;                 // wave col offset (0/64)

  const int n0a = wid * 32;
  const int n0b = wid * 32 + 16;
  const int wrowa = (n0a + (lane >> 2)) * 256 + (lane & 3) * 8;
  const int wrowb = (n0b + (lane >> 2)) * 256 + (lane & 3) * 8;

  int srow1[2]; float scl1[2];
#pragma unroll
  for (int i = 0; i < 2; ++i) {
    const int grow = rowbase + ((tid + i * 256) >> 3);
    srow1[i] = grow; scl1[i] = 1.0f;
    if (perm) { srow1[i] = perm[grow]; scl1[i] = gsc[grow]; }
  }

  f32x4 acc[2][4];
#pragma unroll
  for (int a = 0; a < 2; ++a)
#pragma unroll
    for (int b = 0; b < 4; ++b) acc[a][b] = (f32x4){0.f, 0.f, 0.f, 0.f};

  for (int s = 0; s < 8; ++s) {                  // 8 k-steps of 32 over K=256
    const bool ismean = s < 4;
    const float* sp = ismean ? meanb : xsrc;
    const int kbase = s * 32;
    const int kloc  = ismean ? kbase : kbase - 128;
#pragma unroll
    for (int i = 0; i < 2; ++i) {
      const int p   = tid + i * 256;
      const int row = p >> 3;
      const int k4  = (p & 7) * 4;
      const int srow   = ismean ? (rowbase + row) : srow1[i];
      const float scale = ismean ? 1.0f : scl1[i];
      const float4 v = *(const float4*)(sp + (size_t)srow * kH + kloc + k4);
      float f[4] = {v.x * scale, v.y * scale, v.z * scale, v.w * scale};
      uint hh[2], ll[2];
      cvt4(f, hh, ll);
      *(uint2*)&aH[row][k4] = make_uint2(hh[0], hh[1]);
      *(uint2*)&aL[row][k4] = make_uint2(ll[0], ll[1]);
    }
    llds16(WTh + wrowa + kbase, &wHs[n0a][0]);
    llds16(WTh + wrowb + kbase, &wHs[n0b][0]);
    llds16(WTl + wrowa + kbase, &wLs[n0a][0]);
    llds16(WTl + wrowb + kbase, &wLs[n0b][0]);
    __syncthreads();
    bf16x8 afh[2], afl[2];
#pragma unroll
    for (int rt = 0; rt < 2; ++rt) {
      afh[rt] = *(const bf16x8*)&aH[wr + rt * 16 + l16][quad * 8];
      afl[rt] = *(const bf16x8*)&aL[wr + rt * 16 + l16][quad * 8];
    }
#pragma unroll
    for (int ct = 0; ct < 4; ++ct) {
      const bf16x8 bh = *(const bf16x8*)&wHs[wc + ct * 16 + l16][quad * 8];
      const bf16x8 bl = *(const bf16x8*)&wLs[wc + ct * 16 + l16][quad * 8];
#pragma unroll
      for (int rt = 0; rt < 2; ++rt) {
        acc[rt][ct] = __builtin_amdgcn_mfma_f32_16x16x32_bf16(afh[rt], bh, acc[rt][ct], 0, 0, 0);
        acc[rt][ct] = __builtin_amdgcn_mfma_f32_16x16x32_bf16(afh[rt], bl, acc[rt][ct], 0, 0, 0);
        acc[rt][ct] = __builtin_amdgcn_mfma_f32_16x16x32_bf16(afl[rt], bh, acc[rt][ct], 0, 0, 0);
      }
    }
    __syncthreads();
  }
  float bv[4], pwv[4];
#pragma unroll
  for (int ct = 0; ct < 4; ++ct) {
    const int col = wc + ct * 16 + l16;
    bv[ct]  = bias[col];
    pwv[ct] = pwn[col];
  }
  float dot[2][4];
#pragma unroll
  for (int rt = 0; rt < 2; ++rt)
#pragma unroll
    for (int reg = 0; reg < 4; ++reg) dot[rt][reg] = 0.0f;
#pragma unroll
  for (int ct = 0; ct < 4; ++ct) {
    const int col = wc + ct * 16 + l16;
#pragma unroll
    for (int rt = 0; rt < 2; ++rt) {
#pragma unroll
      for (int reg = 0; reg < 4; ++reg) {
        const int row = rowbase + wr + rt * 16 + quad * 4 + reg;
        const float o = fmaxf(acc[rt][ct][reg] + bv[ct], 0.0f);
        outp[(size_t)row * kH + col] = o;
        dot[rt][reg] += o * pwv[ct];
      }
    }
  }
#pragma unroll
  for (int rt = 0; rt < 2; ++rt) {
#pragma unroll
    for (int reg = 0; reg < 4; ++reg) {
      float d = dot[rt][reg];
      d += __shfl_xor(d, 1);
      d += __shfl_xor(d, 2);
      d += __shfl_xor(d, 4);
      d += __shfl_xor(d, 8);
      if (l16 == 0) sdot[wr + rt * 16 + quad * 4 + reg][wc >> 6] = d;
    }
  }
  __syncthreads();
  if (tid < 64) scr[rowbase + tid] = tanhf(sdot[tid][0] + sdot[tid][1]);
}

// ====== layer-1 top-K rank + compaction (radix select; proven since R5) =====
__global__ __launch_bounds__(1024)
void rank_compact(const float* __restrict__ scr, int n_per, int K,
                  int* __restrict__ perm, float* __restrict__ gsc,
                  float* __restrict__ gsg) {
  __shared__ int hist[256];
  __shared__ int wsum[16];
  __shared__ uint bT;
  __shared__ int bRem;
  const int g = blockIdx.x, tid = threadIdx.x;
  const float sc = (tid < n_per) ? scr[g * n_per + tid] : -3e30f;  // pad never wins
  const uint key = score_key(sc);

  uint T; int rem;
  radix_select(key, K, hist, &bT, &bRem, T, rem);

  const int gt = (key > T) ? 1 : 0;
  const int eq = (key == T) ? 1 : 0;
  const int incl = block_scan_1024((gt << 11) | eq, wsum);   // internal barriers
  const int excl = incl - ((gt << 11) | eq);
  const int gt_excl = excl >> 11;
  const int eq_excl = excl & 2047;
  const int keep = (tid < n_per) && (gt || (eq && eq_excl < rem));
  if (keep) {
    const int pos = gt_excl + min(eq_excl, rem);
    perm[g * K + pos] = g * n_per + tid;
    gsc[g * K + pos]  = sc;
  }
  if (gsg) gsg[g * kN + tid] = keep ? sc + 2.0f : 0.0f;
}

// ====== fused layer-2 tail (R13 fix): radix-select + gated readout + MLP =====
// R12 post-mortem: 47 us, FETCH 11.2 MB @ 240 GB/s == dur -> latency-bound
// (64 blocks = 1 wave/SIMD; branchy loads = ~1 outstanding/thread). Fix:
// unconditional loads gated arithmetically + 4-deep batched loads (4x MLP).
__global__ __launch_bounds__(1024)
void final_fused(const float* __restrict__ scr, const float* __restrict__ h2,
                 const float* __restrict__ ps1, const float* __restrict__ pm1,
                 const float* __restrict__ fW1, const float* __restrict__ fb1,
                 const float* __restrict__ fW2, const float* __restrict__ fb2,
                 float* __restrict__ out) {
  __shared__ int hist[256];
  __shared__ int wsum[16];
  __shared__ uint bT;
  __shared__ int bRem;
  __shared__ float ls[1024];                 // gated scores (+2 sentinel)
  __shared__ float ss[8][128], sm[8][128];   // readout partials
  __shared__ float xx[256];
  __shared__ float z[128];
  const int g = blockIdx.x, tid = threadIdx.x;
  const int n_per = kK1, K = kK2;

  // ---- top-K select over layer-2 scores ----
  const float sc = (tid < n_per) ? scr[g * n_per + tid] : -3e30f;
  const uint key = score_key(sc);
  uint T; int rem;
  radix_select(key, K, hist, &bT, &bRem, T, rem);
  const int gt = (key > T) ? 1 : 0;
  const int eq = (key == T) ? 1 : 0;
  const int eq_incl = block_scan_1024(eq, wsum);     // tie-break needs eq order
  const int eq_excl = eq_incl - eq;
  const int keep = (tid < n_per) && (gt || (eq && eq_excl < rem));
  ls[tid] = keep ? sc + 2.0f : 0.0f;
  __syncthreads();

  // ---- gated readout of h2: unconditional 4-deep batched loads, gate after --
  const int part = tid >> 7;
  const int j    = tid & 127;
  const float* h2g = h2 + (size_t)g * kK1 * kH + j;
  float sum = 0.0f, mx = -1e30f;
  for (int i = part; i < n_per; i += 32) {
    float v[4], s[4];
#pragma unroll
    for (int u = 0; u < 4; ++u) {
      const int ii = i + u * 8;
      const bool ok = ii < n_per;
      s[u] = ok ? ls[ii] : 0.0f;
      v[u] = ok ? h2g[(size_t)ii * kH] : 0.0f;     // independent loads, 4 in flight
    }
#pragma unroll
    for (int u = 0; u < 4; ++u) {
      const float val = v[u] * (s[u] - 2.0f);
      if (s[u] > 0.5f) { sum += val; mx = fmaxf(mx, val); }
    }
  }
  ss[part][j] = sum;
  sm[part][j] = mx;
  __syncthreads();

  // ---- combine with layer-1 readout + 2-layer MLP head ----
  if (tid < 128) {
    float s2 = 0.0f, m2 = -1e30f;
#pragma unroll
    for (int p = 0; p < 8; ++p) { s2 += ss[p][tid]; m2 = fmaxf(m2, sm[p][tid]); }
    const float s1 = ps1[(size_t)g * 128 + tid];
    const float m1 = pm1[(size_t)g * 128 + tid];
    xx[tid]       = s1 / (float)kK1 + s2 / (float)K;
    xx[tid + 128] = m1 + m2;
  }
  __syncthreads();
  if (tid < 128) {
    float a = fb1[tid];
    for (int k = 0; k < 256; ++k) a += xx[k] * fW1[k * 128 + tid];
    z[tid] = fmaxf(a, 0.0f);
  }
  __syncthreads();
  if (tid < 10) {
    float o = fb2[tid];
    for (int k = 0; k < 128; ++k) o += z[k] * fW2[k * 10 + tid];
    out[g * 10 + tid] = o;
  }
}

}  // namespace

extern "C" void kernel_launch(void* const* d_in, const int* in_sizes, int n_in,
                              void* d_out, int out_size, void* d_ws, size_t ws_size,
                              hipStream_t stream) {
  const float* x   = (const float*)d_in[0];
  const int*   ei  = (const int*)d_in[1];
  const float* Wl1 = (const float*)d_in[3];
  const float* bl1 = (const float*)d_in[4];
  const float* Wr1 = (const float*)d_in[5];
  const float* Wl2 = (const float*)d_in[6];
  const float* bl2 = (const float*)d_in[7];
  const float* Wr2 = (const float*)d_in[8];
  const float* pw1 = (const float*)d_in[9];
  const float* pw2 = (const float*)d_in[10];
  const float* fW1 = (const float*)d_in[11];
  const float* fb1 = (const float*)d_in[12];
  const float* fW2 = (const float*)d_in[13];
  const float* fb2 = (const float*)d_in[14];
  const int* src = ei;
  const int* dst = ei + kE;
  (void)in_sizes; (void)n_in; (void)out_size; (void)ws_size;

  char* wsb = (char*)d_ws;
  size_t off_b = 0;
  auto alloc = [&](size_t bytes) {
    void* p = wsb + off_b;
    off_b += (bytes + 255) & ~(size_t)255;
    return p;
  };
  float* bufA = (float*)alloc((size_t)kM1 * kH * 4);  // mean1 -> mean2
  float* bufB = (float*)alloc((size_t)kM1 * kH * 4);  // h1
  float* bufC = (float*)alloc((size_t)kM2 * kH * 4);  // h2
  int*   coff = (int*)alloc((size_t)kM1 * 4);
  int*   ccur = (int*)alloc((size_t)kM1 * 4);
  int*   ent  = (int*)alloc((size_t)kE * 4);
  float* scr  = (float*)alloc((size_t)kM1 * 4);
  float* gsg  = (float*)alloc((size_t)kM1 * 4);
  int*   perm1= (int*)alloc((size_t)kM2 * 4);
  float* gsc1 = (float*)alloc((size_t)kM2 * 4);
  float* psum1= (float*)alloc((size_t)kB * 128 * 4);  // L1: fully reduced
  float* pmax1= (float*)alloc((size_t)kB * 128 * 4);
  ushort* wt1h = (ushort*)alloc((size_t)128 * 256 * 2);
  ushort* wt1l = (ushort*)alloc((size_t)128 * 256 * 2);
  ushort* wt2h = (ushort*)alloc((size_t)128 * 256 * 2);
  ushort* wt2l = (ushort*)alloc((size_t)128 * 256 * 2);
  float* pwn1 = (float*)alloc(128 * 4);
  float* pwn2 = (float*)alloc(128 * 4);

  // ---------------- fused CSR build + prep ----------------
  build_prep<<<129, 1024, 0, stream>>>(src, dst, coff, ccur, ent,
                                       Wl1, Wr1, Wl2, Wr2, pw1, pw2,
                                       wt1h, wt1l, wt2h, wt2l, pwn1, pwn2);

  // ---------------- layer 1 ----------------
  gather1_lds<<<kB * 8, 1024, 0, stream>>>(x, ent, coff, ccur, bufA);
  sage_gemm_mfma<<<kM1 / 64, 256, 0, stream>>>(bufA, x, nullptr, nullptr,
                                               wt1h, wt1l, bl1, pwn1, bufB, scr);
  rank_compact<<<kB, 1024, 0, stream>>>(scr, kN, kK1, perm1, gsc1, gsg);

  // ---------------- layer 2 (gather2 also emits the layer-1 readout) --------
  gather2_lds<<<kB * 8, 1024, 0, stream>>>(bufB, ent, coff, ccur, perm1, gsg,
                                           bufA, psum1, pmax1);
  sage_gemm_mfma<<<kM2 / 64, 256, 0, stream>>>(bufA, bufB, perm1, gsc1,
                                               wt2h, wt2l, bl2, pwn2, bufC, scr);

  // ---------------- fused tail: L2 rank + gated readout + MLP head ----------
  final_fused<<<kB, 1024, 0, stream>>>(scr, bufC, psum1, pmax1,
                                       fW1, fb1, fW2, fb2, (float*)d_out);
}